// Round 19
// baseline (2518.870 us; speedup 1.0000x reference)
//
#include <hip/hip_runtime.h>

typedef __attribute__((ext_vector_type(8))) __bf16 bf16x8;
typedef __attribute__((ext_vector_type(4))) float f32x4;

#define DEV __device__ __forceinline__

DEV unsigned short f2bf(float f) {
  unsigned int u = __float_as_uint(f);
  u += 0x7FFFu + ((u >> 16) & 1u);   // RNE
  return (unsigned short)(u >> 16);
}

// Branch-free tanh-form GELU (~10 VALU ops, no divergence).
DEV float gelu_fast(float v) {
  float x2 = v * v;
  float u = v * (0.7978845608028654f + 0.035677408136300125f * x2);
  u = fminf(fmaxf(u, -9.f), 9.f);
  float e = __expf(2.f * u);
  float th = (e - 1.f) / (e + 1.f);
  return 0.5f * v * (1.f + th);
}

// ---------------- kernel 1: f32 -> bf16 (vectorized) ----------------
__global__ __launch_bounds__(256) void k_f32_to_bf16(const float* __restrict__ x,
                                                     unsigned short* __restrict__ y) {
  size_t i = ((size_t)blockIdx.x * 256 + threadIdx.x) * 8;
  float4 a = *(const float4*)(x + i);
  float4 b = *(const float4*)(x + i + 4);
  union { unsigned short u[8]; uint4 v; } o;
  o.u[0] = f2bf(a.x); o.u[1] = f2bf(a.y); o.u[2] = f2bf(a.z); o.u[3] = f2bf(a.w);
  o.u[4] = f2bf(b.x); o.u[5] = f2bf(b.y); o.u[6] = f2bf(b.z); o.u[7] = f2bf(b.w);
  *(uint4*)(y + i) = o.v;
}

// ------- kernel 2: AWQ int4 dequant -> W^T bf16 [N][K] (LDS transpose) -------
__global__ __launch_bounds__(256) void k_dequant_t(const int* __restrict__ qw,
                                                   const int* __restrict__ qz,
                                                   const float* __restrict__ sc,
                                                   unsigned short* __restrict__ wt,
                                                   int K, int N) {
  __shared__ __align__(16) unsigned short st[64][72];
  const int k0 = blockIdx.x * 64, n0 = blockIdx.y * 64;
  const int t = threadIdx.x;
  const int g = k0 >> 7;
  const int Np = N >> 3;
#pragma unroll
  for (int it = 0; it < 2; ++it) {
    int idx = t + it * 256;
    int k = idx >> 3;
    int nc = idx & 7;
    unsigned int w = (unsigned int)qw[(size_t)(k0 + k) * Np + (n0 >> 3) + nc];
    unsigned int z = (unsigned int)qz[(size_t)g * Np + (n0 >> 3) + nc];
#pragma unroll
    for (int i = 0; i < 8; ++i) {
      float s = sc[(size_t)g * N + n0 + nc * 8 + i];
      float v = ((float)(int)((w >> (4 * i)) & 0xFu) -
                 (float)(int)((z >> (4 * i)) & 0xFu)) * s;
      st[nc * 8 + i][k] = f2bf(v);
    }
  }
  __syncthreads();
  const int n = t >> 2, c = t & 3;
  uint4 v0 = *(const uint4*)&st[n][c * 16];
  uint4 v1 = *(const uint4*)&st[n][c * 16 + 8];
  unsigned short* dst = wt + (size_t)(n0 + n) * K + k0 + c * 16;
  *(uint4*)dst = v0;
  *(uint4*)(dst + 8) = v1;
}

// ------ kernel 3: 256x256 GEMM, m201-faithful 4-phase/K-tile + counted vmcnt --
// R18 post-mortem: split clusters regressed (setprio pinned order; cluster-0
// stalled on its own reads). R17 champion. NEW attribution: all prior 8-phase
// tests (R2/R5/R7) ran on dirty rasters (FETCH 3.3-4.3GB, dur == fetch/2.6TBps
// -- fabric-bound); the counted-vmcnt phase schedule (T3+T4, +38-73% m218)
// was never compute-evaluated. Retest on the clean raster (FETCH ~1.3GB).
// Per K-tile: 4 phases {reads (8/4, B-reuse) + stage 1 half-slab; barrier;
// setprio(1); 16 MFMA; setprio(0); barrier}; ONE vmcnt(4) per tile at phase-4
// end (never 0 till tail) -- loads span barriers. Ledger == R2's (verified):
// slab h read at tile floor(h/2) is drained by the prior tile's vmcnt(4).

#define STAGE_A(h) do { const unsigned short* g_ = A + gsA + (size_t)(h) * 32;               \
  __builtin_amdgcn_global_load_lds((const __attribute__((address_space(1))) void*)g_,        \
      (__attribute__((address_space(3))) void*)(&sA[(h) & 3][0] + tid * 8), 16, 0, 0);       \
  __builtin_amdgcn_global_load_lds((const __attribute__((address_space(1))) void*)(g_ + (size_t)128 * K), \
      (__attribute__((address_space(3))) void*)(&sA[(h) & 3][4096] + tid * 8), 16, 0, 0); } while (0)
#define STAGE_B(h) do { const unsigned short* g_ = B + gsB + (size_t)(h) * 32;               \
  __builtin_amdgcn_global_load_lds((const __attribute__((address_space(1))) void*)g_,        \
      (__attribute__((address_space(3))) void*)(&sB[(h) & 3][0] + tid * 8), 16, 0, 0);       \
  __builtin_amdgcn_global_load_lds((const __attribute__((address_space(1))) void*)(g_ + (size_t)128 * K), \
      (__attribute__((address_space(3))) void*)(&sB[(h) & 3][4096] + tid * 8), 16, 0, 0); } while (0)

#define LDA(s, m) (*(const bf16x8*)((const char*)&sA[s][0] + offA + (m) * 1024))
#define LDB(s, n) (*(const bf16x8*)((const char*)&sB[s][0] + offB + (n) * 1024))

template <int GELU>
__global__ __launch_bounds__(512, 2) void k_gemm256(const unsigned short* __restrict__ A,
                                                    const unsigned short* __restrict__ B,
                                                    void* __restrict__ C,
                                                    int M, int N, int K) {
  __shared__ __align__(16) unsigned short sA[4][8192];
  __shared__ __align__(16) unsigned short sB[4][8192];
  const int tid = threadIdx.x;
  const int lane = tid & 63;
  const int wave = tid >> 6;
  const int wm = wave >> 2, wn = wave & 3;
  const int r16 = lane & 15, q = lane >> 4;

  // Raster: bijective XCD chunk + grouped-m (GM=16, m-fastest within group).
  const int nbx = N >> 8;
  const int cpx = gridDim.x >> 3;
  const int g = (blockIdx.x & 7) * cpx + (blockIdx.x >> 3);
  const int gw = nbx << 4;
  const int grp = g / gw;
  const int rem = g - grp * gw;
  const int m0 = (grp * 16 + (rem & 15)) * 256;
  const int n0 = (rem >> 4) * 256;

  const int rA = wm * 128 + r16;
  const int rB = wn * 64 + r16;
  const int offA = rA * 64 + ((q * 16) ^ (((rA >> 1) & 3) << 4));
  const int offB = rB * 64 + ((q * 16) ^ (((rB >> 1) & 3) << 4));

  const int sr = tid >> 2;                        // staging row (0..127)
  const int ssrc = (tid & 3) ^ ((sr >> 1) & 3);   // pre-swizzled global 16B slot
  const size_t gsA = (size_t)(m0 + sr) * K + (size_t)ssrc * 8;
  const size_t gsB = (size_t)(n0 + sr) * K + (size_t)ssrc * 8;

  f32x4 acc[8][4] = {};
  const int NT = K >> 6;

  // prologue: slabs 0,1,2 staged (12 DMA); vmcnt(4) => slabs 0,1 resident
  STAGE_A(0); STAGE_B(0); STAGE_A(1); STAGE_B(1); STAGE_A(2); STAGE_B(2);
  asm volatile("s_waitcnt vmcnt(4)" ::: "memory");
  __builtin_amdgcn_s_barrier();

  for (int t = 0; t < NT; ++t) {
    const int s0 = (2 * t) & 3, s1 = (2 * t + 1) & 3;
    const int h3 = 2 * t + 3, h4 = 2 * t + 4;
    bf16x8 af[4], bf[4];

    // ---- phase 1: kk0, m0-3 (8 reads) ; stage A(2t+3)
#pragma unroll
    for (int j = 0; j < 4; ++j) bf[j] = LDB(s0, j);
#pragma unroll
    for (int i = 0; i < 4; ++i) af[i] = LDA(s0, i);
    if (h3 < 2 * NT) STAGE_A(h3);
    __builtin_amdgcn_s_barrier();
    __builtin_amdgcn_s_setprio(1);
#pragma unroll
    for (int i = 0; i < 4; ++i)
#pragma unroll
      for (int j = 0; j < 4; ++j)
        acc[i][j] = __builtin_amdgcn_mfma_f32_16x16x32_bf16(af[i], bf[j], acc[i][j], 0, 0, 0);
    __builtin_amdgcn_s_setprio(0);
    __builtin_amdgcn_s_barrier();

    // ---- phase 2: kk0, m4-7 (4 reads, B reused) ; stage B(2t+3)
#pragma unroll
    for (int i = 0; i < 4; ++i) af[i] = LDA(s0, 4 + i);
    if (h3 < 2 * NT) STAGE_B(h3);
    __builtin_amdgcn_s_barrier();
    __builtin_amdgcn_s_setprio(1);
#pragma unroll
    for (int i = 0; i < 4; ++i)
#pragma unroll
      for (int j = 0; j < 4; ++j)
        acc[4 + i][j] = __builtin_amdgcn_mfma_f32_16x16x32_bf16(af[i], bf[j], acc[4 + i][j], 0, 0, 0);
    __builtin_amdgcn_s_setprio(0);
    __builtin_amdgcn_s_barrier();

    // ---- phase 3: kk1, m0-3 (8 reads) ; stage A(2t+4)
#pragma unroll
    for (int j = 0; j < 4; ++j) bf[j] = LDB(s1, j);
#pragma unroll
    for (int i = 0; i < 4; ++i) af[i] = LDA(s1, i);
    if (h4 < 2 * NT) STAGE_A(h4);
    __builtin_amdgcn_s_barrier();
    __builtin_amdgcn_s_setprio(1);
#pragma unroll
    for (int i = 0; i < 4; ++i)
#pragma unroll
      for (int j = 0; j < 4; ++j)
        acc[i][j] = __builtin_amdgcn_mfma_f32_16x16x32_bf16(af[i], bf[j], acc[i][j], 0, 0, 0);
    __builtin_amdgcn_s_setprio(0);
    __builtin_amdgcn_s_barrier();

    // ---- phase 4: kk1, m4-7 (4 reads) ; stage B(2t+4) ; tile-end vmcnt
#pragma unroll
    for (int i = 0; i < 4; ++i) af[i] = LDA(s1, 4 + i);
    if (h4 < 2 * NT) STAGE_B(h4);
    __builtin_amdgcn_s_barrier();
    __builtin_amdgcn_s_setprio(1);
#pragma unroll
    for (int i = 0; i < 4; ++i)
#pragma unroll
      for (int j = 0; j < 4; ++j)
        acc[4 + i][j] = __builtin_amdgcn_mfma_f32_16x16x32_bf16(af[i], bf[j], acc[4 + i][j], 0, 0, 0);
    __builtin_amdgcn_s_setprio(0);
    if (t < NT - 2) { asm volatile("s_waitcnt vmcnt(4)" ::: "memory"); }
    else            { asm volatile("s_waitcnt vmcnt(0)" ::: "memory"); }
    __builtin_amdgcn_s_barrier();
  }

  // epilogue: C/D layout col=lane&15, row=(lane>>4)*4+reg
  const int mb = m0 + wm * 128 + q * 4;
  const int nb = n0 + wn * 64 + r16;
#pragma unroll
  for (int i = 0; i < 8; ++i) {
#pragma unroll
    for (int j = 0; j < 4; ++j) {
#pragma unroll
      for (int r = 0; r < 4; ++r) {
        int row = mb + i * 16 + r;
        int col = nb + j * 16;
        float v = acc[i][j][r];
        if (GELU) {
          v = gelu_fast(v);
          ((unsigned short*)C)[(size_t)row * N + col] = f2bf(v);
        } else {
          ((float*)C)[(size_t)row * N + col] = v;
        }
      }
    }
  }
}

extern "C" void kernel_launch(void* const* d_in, const int* in_sizes, int n_in,
                              void* d_out, int out_size, void* d_ws, size_t ws_size,
                              hipStream_t stream) {
  const float* x  = (const float*)d_in[0];
  const int* uqw  = (const int*)d_in[1];
  const int* uqz  = (const int*)d_in[2];
  const float* usc = (const float*)d_in[3];
  const int* dqw  = (const int*)d_in[4];
  const int* dqz  = (const int*)d_in[5];
  const float* dsc = (const float*)d_in[6];
  float* out = (float*)d_out;

  const int T = 8192, D = 4096, F = 16384;
  char* ws = (char*)d_ws;
  unsigned short* xb = (unsigned short*)ws;                                  // 64 MiB
  unsigned short* h  = (unsigned short*)(ws + (size_t)T * D * 2);            // 256 MiB
  unsigned short* wt = (unsigned short*)(ws + (size_t)T * D * 2 + (size_t)T * F * 2); // 128 MiB

  k_f32_to_bf16<<<dim3((T * D) / (256 * 8)), 256, 0, stream>>>(x, xb);
  k_dequant_t<<<dim3(D / 64, F / 64), 256, 0, stream>>>(uqw, uqz, usc, wt, D, F);
  k_gemm256<1><<<dim3((T / 256) * (F / 256)), 512, 0, stream>>>(xb, wt, (void*)h, T, F, D);
  k_dequant_t<<<dim3(F / 64, D / 64), 256, 0, stream>>>(dqw, dqz, dsc, wt, F, D);
  k_gemm256<0><<<dim3((T / 256) * (D / 256)), 512, 0, stream>>>(h, wt, (void*)out, T, D, F);
}

// Round 20
// 2458.040 us; speedup vs baseline: 1.0247x; 1.0247x over previous
//
#include <hip/hip_runtime.h>

typedef __attribute__((ext_vector_type(8))) __bf16 bf16x8;
typedef __attribute__((ext_vector_type(4))) float f32x4;

#define DEV __device__ __forceinline__

DEV unsigned short f2bf(float f) {
  unsigned int u = __float_as_uint(f);
  u += 0x7FFFu + ((u >> 16) & 1u);   // RNE
  return (unsigned short)(u >> 16);
}

// Branch-free tanh-form GELU (~10 VALU ops, no divergence).
DEV float gelu_fast(float v) {
  float x2 = v * v;
  float u = v * (0.7978845608028654f + 0.035677408136300125f * x2);
  u = fminf(fmaxf(u, -9.f), 9.f);
  float e = __expf(2.f * u);
  float th = (e - 1.f) / (e + 1.f);
  return 0.5f * v * (1.f + th);
}

// ---------------- kernel 1: f32 -> bf16 (vectorized) ----------------
__global__ __launch_bounds__(256) void k_f32_to_bf16(const float* __restrict__ x,
                                                     unsigned short* __restrict__ y) {
  size_t i = ((size_t)blockIdx.x * 256 + threadIdx.x) * 8;
  float4 a = *(const float4*)(x + i);
  float4 b = *(const float4*)(x + i + 4);
  union { unsigned short u[8]; uint4 v; } o;
  o.u[0] = f2bf(a.x); o.u[1] = f2bf(a.y); o.u[2] = f2bf(a.z); o.u[3] = f2bf(a.w);
  o.u[4] = f2bf(b.x); o.u[5] = f2bf(b.y); o.u[6] = f2bf(b.z); o.u[7] = f2bf(b.w);
  *(uint4*)(y + i) = o.v;
}

// ------- kernel 2: AWQ int4 dequant -> W^T bf16 [N][K] (LDS transpose) -------
__global__ __launch_bounds__(256) void k_dequant_t(const int* __restrict__ qw,
                                                   const int* __restrict__ qz,
                                                   const float* __restrict__ sc,
                                                   unsigned short* __restrict__ wt,
                                                   int K, int N) {
  __shared__ __align__(16) unsigned short st[64][72];
  const int k0 = blockIdx.x * 64, n0 = blockIdx.y * 64;
  const int t = threadIdx.x;
  const int g = k0 >> 7;
  const int Np = N >> 3;
#pragma unroll
  for (int it = 0; it < 2; ++it) {
    int idx = t + it * 256;
    int k = idx >> 3;
    int nc = idx & 7;
    unsigned int w = (unsigned int)qw[(size_t)(k0 + k) * Np + (n0 >> 3) + nc];
    unsigned int z = (unsigned int)qz[(size_t)g * Np + (n0 >> 3) + nc];
#pragma unroll
    for (int i = 0; i < 8; ++i) {
      float s = sc[(size_t)g * N + n0 + nc * 8 + i];
      float v = ((float)(int)((w >> (4 * i)) & 0xFu) -
                 (float)(int)((z >> (4 * i)) & 0xFu)) * s;
      st[nc * 8 + i][k] = f2bf(v);
    }
  }
  __syncthreads();
  const int n = t >> 2, c = t & 3;
  uint4 v0 = *(const uint4*)&st[n][c * 16];
  uint4 v1 = *(const uint4*)&st[n][c * 16 + 8];
  unsigned short* dst = wt + (size_t)(n0 + n) * K + k0 + c * 16;
  *(uint4*)dst = v0;
  *(uint4*)(dst + 8) = v1;
}

// ------ kernel 3: 256x256 GEMM, 16 waves x 64x64, 4 waves/SIMD ---------------
// R19 post-mortem: phase-schedule family closed (barrier-heavy tiles ->
// inter-block drift -> L3 thrash -> fabric-bound; FETCH 3.4GB returned).
// R17 budget: 5063 cyc/tile = MFMA 2483 + LDS-read 2304 barely overlapped --
// occupancy-capped at 2 waves/SIMD by per-wave regs (acc128+dbuf). This
// round: SAME 256^2 tile, 1-sync/tile, but 1024 threads = 16 waves of 64x64
// out. acc 64 + single frag set 32 + addr ~16 <= 128 VGPR -> 16 waves/CU =
// 4 waves/SIMD; TLP (m97/m114) hides reads under other waves' MFMA, no
// reg-dbuf needed. LDS reads/tile rise 192->256 instr (duplication 4x4) but
// pipe floors now max() not sum(): ~3600 cyc/tile predicted.

#define STAGE_A(h) do { const unsigned short* g_ = A + gsA + (size_t)(h) * 32;               \
  __builtin_amdgcn_global_load_lds((const __attribute__((address_space(1))) void*)g_,        \
      (__attribute__((address_space(3))) void*)(&sA[(h) & 3][0] + tid * 8), 16, 0, 0); } while (0)
#define STAGE_B(h) do { const unsigned short* g_ = B + gsB + (size_t)(h) * 32;               \
  __builtin_amdgcn_global_load_lds((const __attribute__((address_space(1))) void*)g_,        \
      (__attribute__((address_space(3))) void*)(&sB[(h) & 3][0] + tid * 8), 16, 0, 0); } while (0)

#define LDA(s, m) (*(const bf16x8*)((const char*)&sA[s][0] + offA + (m) * 1024))
#define LDB(s, n) (*(const bf16x8*)((const char*)&sB[s][0] + offB + (n) * 1024))

template <int GELU>
__global__ __launch_bounds__(1024, 1) void k_gemm256(const unsigned short* __restrict__ A,
                                                     const unsigned short* __restrict__ B,
                                                     void* __restrict__ C,
                                                     int M, int N, int K) {
  __shared__ __align__(16) unsigned short sA[4][8192];
  __shared__ __align__(16) unsigned short sB[4][8192];
  const int tid = threadIdx.x;
  const int lane = tid & 63;
  const int wave = tid >> 6;            // 16 waves: wm = wave>>2, wn = wave&3
  const int wm = wave >> 2, wn = wave & 3;
  const int r16 = lane & 15, q = lane >> 4;

  // Raster: bijective XCD chunk + grouped-m (GM=16, m-fastest within group).
  const int nbx = N >> 8;
  const int cpx = gridDim.x >> 3;
  const int g = (blockIdx.x & 7) * cpx + (blockIdx.x >> 3);
  const int gw = nbx << 4;
  const int grp = g / gw;
  const int rem = g - grp * gw;
  const int m0 = (grp * 16 + (rem & 15)) * 256;
  const int n0 = (rem >> 4) * 256;

  const int rA = wm * 64 + r16;
  const int rB = wn * 64 + r16;
  const int offA = rA * 64 + ((q * 16) ^ (((rA >> 1) & 3) << 4));
  const int offB = rB * 64 + ((q * 16) ^ (((rB >> 1) & 3) << 4));

  const int sr = tid >> 2;                        // staging row (0..255)
  const int ssrc = (tid & 3) ^ ((sr >> 1) & 3);   // pre-swizzled global 16B slot
  const size_t gsA = (size_t)(m0 + sr) * K + (size_t)ssrc * 8;
  const size_t gsB = (size_t)(n0 + sr) * K + (size_t)ssrc * 8;

  f32x4 acc[4][4] = {};
  bf16x8 af[4], bf[4];
  const int NT = K >> 6;

  // prologue: stage slabs 0,1 (slots 0,1); loop-top sync covers the rest
  STAGE_A(0); STAGE_B(0); STAGE_A(1); STAGE_B(1);

  for (int t = 0; t < NT; ++t) {
    const int s0 = (2 * t) & 3, s1 = (2 * t + 1) & 3;

    // ---- single sync per tile: own-DMA drain + publish
    asm volatile("s_waitcnt vmcnt(0)" ::: "memory");
    __builtin_amdgcn_s_barrier();

    // ---- stage next tile's slabs first (issue early, land by next tile)
    if (t < NT - 1) {
      STAGE_A(2 * t + 2); STAGE_B(2 * t + 2);
      STAGE_A(2 * t + 3); STAGE_B(2 * t + 3);
    }

    // ---- slab s0: 8 reads + 16 MFMA (compiler interleaves via lgkm waits)
#pragma unroll
    for (int j = 0; j < 4; ++j) bf[j] = LDB(s0, j);
#pragma unroll
    for (int i = 0; i < 4; ++i) af[i] = LDA(s0, i);
#pragma unroll
    for (int i = 0; i < 4; ++i)
#pragma unroll
      for (int j = 0; j < 4; ++j)
        acc[i][j] = __builtin_amdgcn_mfma_f32_16x16x32_bf16(af[i], bf[j], acc[i][j], 0, 0, 0);

    // ---- slab s1: 8 reads + 16 MFMA
#pragma unroll
    for (int j = 0; j < 4; ++j) bf[j] = LDB(s1, j);
#pragma unroll
    for (int i = 0; i < 4; ++i) af[i] = LDA(s1, i);
#pragma unroll
    for (int i = 0; i < 4; ++i)
#pragma unroll
      for (int j = 0; j < 4; ++j)
        acc[i][j] = __builtin_amdgcn_mfma_f32_16x16x32_bf16(af[i], bf[j], acc[i][j], 0, 0, 0);
  }

  // epilogue: C/D layout col=lane&15, row=(lane>>4)*4+reg
  const int mb = m0 + wm * 64 + q * 4;
  const int nb = n0 + wn * 64 + r16;
#pragma unroll
  for (int i = 0; i < 4; ++i) {
#pragma unroll
    for (int j = 0; j < 4; ++j) {
#pragma unroll
      for (int r = 0; r < 4; ++r) {
        int row = mb + i * 16 + r;
        int col = nb + j * 16;
        float v = acc[i][j][r];
        if (GELU) {
          v = gelu_fast(v);
          ((unsigned short*)C)[(size_t)row * N + col] = f2bf(v);
        } else {
          ((float*)C)[(size_t)row * N + col] = v;
        }
      }
    }
  }
}

extern "C" void kernel_launch(void* const* d_in, const int* in_sizes, int n_in,
                              void* d_out, int out_size, void* d_ws, size_t ws_size,
                              hipStream_t stream) {
  const float* x  = (const float*)d_in[0];
  const int* uqw  = (const int*)d_in[1];
  const int* uqz  = (const int*)d_in[2];
  const float* usc = (const float*)d_in[3];
  const int* dqw  = (const int*)d_in[4];
  const int* dqz  = (const int*)d_in[5];
  const float* dsc = (const float*)d_in[6];
  float* out = (float*)d_out;

  const int T = 8192, D = 4096, F = 16384;
  char* ws = (char*)d_ws;
  unsigned short* xb = (unsigned short*)ws;                                  // 64 MiB
  unsigned short* h  = (unsigned short*)(ws + (size_t)T * D * 2);            // 256 MiB
  unsigned short* wt = (unsigned short*)(ws + (size_t)T * D * 2 + (size_t)T * F * 2); // 128 MiB

  k_f32_to_bf16<<<dim3((T * D) / (256 * 8)), 256, 0, stream>>>(x, xb);
  k_dequant_t<<<dim3(D / 64, F / 64), 256, 0, stream>>>(uqw, uqz, usc, wt, D, F);
  k_gemm256<1><<<dim3((T / 256) * (F / 256)), 1024, 0, stream>>>(xb, wt, (void*)h, T, F, D);
  k_dequant_t<<<dim3(F / 64, D / 64), 256, 0, stream>>>(dqw, dqz, dsc, wt, F, D);
  k_gemm256<0><<<dim3((T / 256) * (D / 256)), 1024, 0, stream>>>(h, wt, (void*)out, T, D, F);
}

// Round 21
// 2297.987 us; speedup vs baseline: 1.0961x; 1.0696x over previous
//
#include <hip/hip_runtime.h>

typedef __attribute__((ext_vector_type(8))) __bf16 bf16x8;
typedef __attribute__((ext_vector_type(16))) float f32x16;

#define DEV __device__ __forceinline__

DEV unsigned short f2bf(float f) {
  unsigned int u = __float_as_uint(f);
  u += 0x7FFFu + ((u >> 16) & 1u);   // RNE
  return (unsigned short)(u >> 16);
}

// Branch-free tanh-form GELU (~10 VALU ops, no divergence).
DEV float gelu_fast(float v) {
  float x2 = v * v;
  float u = v * (0.7978845608028654f + 0.035677408136300125f * x2);
  u = fminf(fmaxf(u, -9.f), 9.f);
  float e = __expf(2.f * u);
  float th = (e - 1.f) / (e + 1.f);
  return 0.5f * v * (1.f + th);
}

// ---------------- kernel 1: f32 -> bf16 (vectorized) ----------------
__global__ __launch_bounds__(256) void k_f32_to_bf16(const float* __restrict__ x,
                                                     unsigned short* __restrict__ y) {
  size_t i = ((size_t)blockIdx.x * 256 + threadIdx.x) * 8;
  float4 a = *(const float4*)(x + i);
  float4 b = *(const float4*)(x + i + 4);
  union { unsigned short u[8]; uint4 v; } o;
  o.u[0] = f2bf(a.x); o.u[1] = f2bf(a.y); o.u[2] = f2bf(a.z); o.u[3] = f2bf(a.w);
  o.u[4] = f2bf(b.x); o.u[5] = f2bf(b.y); o.u[6] = f2bf(b.z); o.u[7] = f2bf(b.w);
  *(uint4*)(y + i) = o.v;
}

// ------- kernel 2: AWQ int4 dequant -> W^T bf16 [N][K] (LDS transpose) -------
__global__ __launch_bounds__(256) void k_dequant_t(const int* __restrict__ qw,
                                                   const int* __restrict__ qz,
                                                   const float* __restrict__ sc,
                                                   unsigned short* __restrict__ wt,
                                                   int K, int N) {
  __shared__ __align__(16) unsigned short st[64][72];
  const int k0 = blockIdx.x * 64, n0 = blockIdx.y * 64;
  const int t = threadIdx.x;
  const int g = k0 >> 7;
  const int Np = N >> 3;
#pragma unroll
  for (int it = 0; it < 2; ++it) {
    int idx = t + it * 256;
    int k = idx >> 3;
    int nc = idx & 7;
    unsigned int w = (unsigned int)qw[(size_t)(k0 + k) * Np + (n0 >> 3) + nc];
    unsigned int z = (unsigned int)qz[(size_t)g * Np + (n0 >> 3) + nc];
#pragma unroll
    for (int i = 0; i < 8; ++i) {
      float s = sc[(size_t)g * N + n0 + nc * 8 + i];
      float v = ((float)(int)((w >> (4 * i)) & 0xFu) -
                 (float)(int)((z >> (4 * i)) & 0xFu)) * s;
      st[nc * 8 + i][k] = f2bf(v);
    }
  }
  __syncthreads();
  const int n = t >> 2, c = t & 3;
  uint4 v0 = *(const uint4*)&st[n][c * 16];
  uint4 v1 = *(const uint4*)&st[n][c * 16 + 8];
  unsigned short* dst = wt + (size_t)(n0 + n) * K + k0 + c * 16;
  *(uint4*)dst = v0;
  *(uint4*)(dst + 8) = v1;
}

// ------ kernel 3: 256x256 GEMM, ONE sync/tile, 32x32x16 MFMA -----------------
// R20 post-mortem: occupancy refuted (4 waves/SIMD -> MfmaUtil DROPPED; 33%
// more LDS-read duplication ate the TLP gain). R17 champion; budget = MFMA
// 2483 + LDS 2304 + sync. Last lever: MFMA shape. 32x32x16 bf16 = 32768 FLOP
// @ ~8.07 cyc (2495 TF ceiling) vs 16x16x32's 16384 @ 4.85 (2075) -> ~17%
// fewer MFMA cycles, half the instructions, SAME ds_read count/bytes (per
// tile: 4 steps x {4 A + 2 B} b128 reads/wave). acc f32x16[4][2] = 128 regs
// (unchanged). C/D map (m74/m101, asym-verified): col=lane&31,
// row=(reg&3)+8*(reg>>2)+4*(lane>>5). Bank-uniform under existing swizzle
// (hand-checked: exactly 8 words/bank/access = minimum).

#define STAGE_A(h) do { const unsigned short* g_ = A + gsA + (size_t)(h) * 32;               \
  __builtin_amdgcn_global_load_lds((const __attribute__((address_space(1))) void*)g_,        \
      (__attribute__((address_space(3))) void*)(&sA[(h) & 3][0] + tid * 8), 16, 0, 0);       \
  __builtin_amdgcn_global_load_lds((const __attribute__((address_space(1))) void*)(g_ + (size_t)128 * K), \
      (__attribute__((address_space(3))) void*)(&sA[(h) & 3][4096] + tid * 8), 16, 0, 0); } while (0)
#define STAGE_B(h) do { const unsigned short* g_ = B + gsB + (size_t)(h) * 32;               \
  __builtin_amdgcn_global_load_lds((const __attribute__((address_space(1))) void*)g_,        \
      (__attribute__((address_space(3))) void*)(&sB[(h) & 3][0] + tid * 8), 16, 0, 0);       \
  __builtin_amdgcn_global_load_lds((const __attribute__((address_space(1))) void*)(g_ + (size_t)128 * K), \
      (__attribute__((address_space(3))) void*)(&sB[(h) & 3][4096] + tid * 8), 16, 0, 0); } while (0)

// 32x32x16 fragment read: step ss in [0,4) within a tile; slab = ss>>1, half = ss&1.
// lane l: row = base + (l&31); k-byte = (ss&1)*32 + (l>>5)*16, XOR row-swizzle.
#define LDA32(s, mi, ss) (*(const bf16x8*)((const char*)&sA[s][0] + baseA[mi] + ((((ss) & 1) * 32 + h16) ^ swzA[mi])))
#define LDB32(s, nj, ss) (*(const bf16x8*)((const char*)&sB[s][0] + baseB[nj] + ((((ss) & 1) * 32 + h16) ^ swzB[nj])))

template <int GELU>
__global__ __launch_bounds__(512, 2) void k_gemm256(const unsigned short* __restrict__ A,
                                                    const unsigned short* __restrict__ B,
                                                    void* __restrict__ C,
                                                    int M, int N, int K) {
  __shared__ __align__(16) unsigned short sA[4][8192];
  __shared__ __align__(16) unsigned short sB[4][8192];
  const int tid = threadIdx.x;
  const int lane = tid & 63;
  const int wave = tid >> 6;
  const int wm = wave >> 2, wn = wave & 3;
  const int l31 = lane & 31;
  const int h16 = (lane >> 5) * 16;    // 16B half-select within a row's k-range

  // Raster: bijective XCD chunk + grouped-m (GM=16, m-fastest within group).
  const int nbx = N >> 8;
  const int cpx = gridDim.x >> 3;
  const int g = (blockIdx.x & 7) * cpx + (blockIdx.x >> 3);
  const int gw = nbx << 4;
  const int grp = g / gw;
  const int rem = g - grp * gw;
  const int m0 = (grp * 16 + (rem & 15)) * 256;
  const int n0 = (rem >> 4) * 256;

  // per-fragment row bases and swizzles
  int baseA[4], swzA[4], baseB[2], swzB[2];
#pragma unroll
  for (int mi = 0; mi < 4; ++mi) {
    int r = wm * 128 + mi * 32 + l31;
    baseA[mi] = r * 64;
    swzA[mi] = ((r >> 1) & 3) << 4;
  }
#pragma unroll
  for (int nj = 0; nj < 2; ++nj) {
    int r = wn * 64 + nj * 32 + l31;
    baseB[nj] = r * 64;
    swzB[nj] = ((r >> 1) & 3) << 4;
  }

  const int sr = tid >> 2;                        // staging row (0..127)
  const int ssrc = (tid & 3) ^ ((sr >> 1) & 3);   // pre-swizzled global 16B slot
  const size_t gsA = (size_t)(m0 + sr) * K + (size_t)ssrc * 8;
  const size_t gsB = (size_t)(n0 + sr) * K + (size_t)ssrc * 8;

  f32x16 acc[4][2] = {};
  bf16x8 af[4][4], bf[4][2];
  const int NT = K >> 6;

  // prologue: stage slabs 0,1 (slots 0,1); loop-top sync covers the rest
  STAGE_A(0); STAGE_B(0); STAGE_A(1); STAGE_B(1);

  for (int t = 0; t < NT; ++t) {
    const int s0 = (2 * t) & 3, s1 = (2 * t + 1) & 3;

    // ---- single sync per tile: own-DMA drain, then publish via barrier
    asm volatile("s_waitcnt vmcnt(0)" ::: "memory");
    __builtin_amdgcn_s_barrier();

    // ---- 24 frag reads: steps 0,1 from slab s0; steps 2,3 from slab s1
#pragma unroll
    for (int st = 0; st < 4; ++st) {
      const int sl = (st < 2) ? s0 : s1;
#pragma unroll
      for (int nj = 0; nj < 2; ++nj) bf[st][nj] = LDB32(sl, nj, st);
#pragma unroll
      for (int mi = 0; mi < 4; ++mi) af[st][mi] = LDA32(sl, mi, st);
    }

    // ---- stage next tile's slabs into the other two ring slots
    if (t < NT - 1) {
      STAGE_A(2 * t + 2); STAGE_B(2 * t + 2);
      STAGE_A(2 * t + 3); STAGE_B(2 * t + 3);
    }

    // ---- 32 MFMA (first cluster starts as soon as its 6 reads land)
    __builtin_amdgcn_s_setprio(1);
#pragma unroll
    for (int st = 0; st < 4; ++st)
#pragma unroll
      for (int mi = 0; mi < 4; ++mi)
#pragma unroll
        for (int nj = 0; nj < 2; ++nj)
          acc[mi][nj] = __builtin_amdgcn_mfma_f32_32x32x16_bf16(af[st][mi], bf[st][nj], acc[mi][nj], 0, 0, 0);
    __builtin_amdgcn_s_setprio(0);
  }

  // epilogue: 32x32 C/D layout col=lane&31, row=(reg&3)+8*(reg>>2)+4*(lane>>5)
  const int mb = m0 + wm * 128 + 4 * (lane >> 5);
  const int nb = n0 + wn * 64 + l31;
#pragma unroll
  for (int mi = 0; mi < 4; ++mi) {
#pragma unroll
    for (int nj = 0; nj < 2; ++nj) {
#pragma unroll
      for (int r = 0; r < 16; ++r) {
        int row = mb + mi * 32 + (r & 3) + 8 * (r >> 2);
        int col = nb + nj * 32;
        float v = acc[mi][nj][r];
        if (GELU) {
          v = gelu_fast(v);
          ((unsigned short*)C)[(size_t)row * N + col] = f2bf(v);
        } else {
          ((float*)C)[(size_t)row * N + col] = v;
        }
      }
    }
  }
}

extern "C" void kernel_launch(void* const* d_in, const int* in_sizes, int n_in,
                              void* d_out, int out_size, void* d_ws, size_t ws_size,
                              hipStream_t stream) {
  const float* x  = (const float*)d_in[0];
  const int* uqw  = (const int*)d_in[1];
  const int* uqz  = (const int*)d_in[2];
  const float* usc = (const float*)d_in[3];
  const int* dqw  = (const int*)d_in[4];
  const int* dqz  = (const int*)d_in[5];
  const float* dsc = (const float*)d_in[6];
  float* out = (float*)d_out;

  const int T = 8192, D = 4096, F = 16384;
  char* ws = (char*)d_ws;
  unsigned short* xb = (unsigned short*)ws;                                  // 64 MiB
  unsigned short* h  = (unsigned short*)(ws + (size_t)T * D * 2);            // 256 MiB
  unsigned short* wt = (unsigned short*)(ws + (size_t)T * D * 2 + (size_t)T * F * 2); // 128 MiB

  k_f32_to_bf16<<<dim3((T * D) / (256 * 8)), 256, 0, stream>>>(x, xb);
  k_dequant_t<<<dim3(D / 64, F / 64), 256, 0, stream>>>(uqw, uqz, usc, wt, D, F);
  k_gemm256<1><<<dim3((T / 256) * (F / 256)), 512, 0, stream>>>(xb, wt, (void*)h, T, F, D);
  k_dequant_t<<<dim3(F / 64, D / 64), 256, 0, stream>>>(dqw, dqz, dsc, wt, F, D);
  k_gemm256<0><<<dim3((T / 256) * (D / 256)), 512, 0, stream>>>(h, wt, (void*)out, T, D, F);
}